// Round 4
// baseline (7954.451 us; speedup 1.0000x reference)
//
#include <hip/hip_runtime.h>

// Problem: B=64, T=512, I=256, H=512, C=128. LSTM forward (truncation is a
// forward no-op) + final linear projection. fp32 in/out; bf16 MFMA inside.
#define B_ 64
#define T_ 512
#define I_ 256
#define H_ 512
#define C_ 128
#define NWG 64                // one wg per 8 h-columns; 32 gate rows each
#define HS_ELEMS ((size_t)T_ * B_ * H_)          // bf16 h archive/broadcast
#define HS_BYTES (HS_ELEMS * 2)                  // 32 MB
#define SENT 0xFFFFFFFFFFFFFFFFull               // 4x bf16 NaN: h can't be NaN

typedef __bf16 bf16x8 __attribute__((ext_vector_type(8)));
typedef float f32x4 __attribute__((ext_vector_type(4)));
typedef unsigned long long u64x2 __attribute__((ext_vector_type(2)));

__device__ __forceinline__ bf16x8 cvt8(const float4 a, const float4 b) {
    bf16x8 r;
    r[0] = (__bf16)a.x; r[1] = (__bf16)a.y; r[2] = (__bf16)a.z; r[3] = (__bf16)a.w;
    r[4] = (__bf16)b.x; r[5] = (__bf16)b.y; r[6] = (__bf16)b.z; r[7] = (__bf16)b.w;
    return r;
}

__device__ __forceinline__ float sigm(float x) {
    return __frcp_rn(1.0f + __expf(-x));
}
__device__ __forceinline__ float tanh_(float x) {
    return 2.0f * sigm(2.0f * x) - 1.0f;
}

// ---------------------------------------------------------------------------
// Recurrent kernel: 64 wgs x 512 threads (8 waves). wg p owns h columns
// [8p, 8p+8). Weights stationary in VGPRs.
//
// Sync design v3 — DATA-AS-FLAG (no flags at all):
//   hs is pre-memset to 0xFF; bf16 0xFFFF is NaN and h=o*tanh(c) is never
//   NaN, so a u64 packet (4 bf16) is either sentinel or complete (each
//   packet is written by ONE atomic 8-B sc1 store -> never partial).
//   Producers (wave 0 of each wg) store h straight to L3 and move on:
//   no vmcnt drain, no flag store, no release. Consumers poll their OWN
//   A-fragment packets until != sentinel: the poll IS the load. Per-step
//   dependency chain = ONE L3 store->load hop (was 4 round trips).
//   Chunk-poll order is rotated per-wg to spread L3 pressure.
// ---------------------------------------------------------------------------
__global__ void __launch_bounds__(512, 2)
lstm_kernel(const float* __restrict__ x, const float* __restrict__ W_ih,
            const float* __restrict__ W_hh, const float* __restrict__ b_ih,
            const float* __restrict__ b_hh, unsigned short* __restrict__ hs)
{
    const int p    = blockIdx.x;          // 0..63
    const int tid  = threadIdx.x;
    const int w    = tid >> 6;            // wave 0..7
    const int lane = tid & 63;
    const int l15  = lane & 15;
    const int quad = lane >> 4;
    const int mt   = w >> 1;              // b-tile 0..3
    const int nt   = w & 1;               // gate-col tile 0..1
    const int arow = mt * 16 + l15;       // A-operand row (batch index b)

    __shared__ float gates_lds[64 * 33];          // [b][jl], pad 33
    __shared__ unsigned short h_tile[64 * 8];     // [b][w] gathered h (bf16)

    // ---- stationary weight fragments (B operand: B[k][n], n = lane&15) ----
    const int jl = nt * 16 + l15;                         // 0..31 within slice
    const int J  = (jl >> 3) * H_ + p * 8 + (jl & 7);     // global gate row
    bf16x8 wh[16], wi[8];
#pragma unroll
    for (int kc = 0; kc < 16; ++kc) {
        const float* sp = W_hh + (size_t)J * H_ + kc * 32 + quad * 8;
        wh[kc] = cvt8(((const float4*)sp)[0], ((const float4*)sp)[1]);
    }
#pragma unroll
    for (int kc = 0; kc < 8; ++kc) {
        const float* sp = W_ih + (size_t)J * I_ + kc * 32 + quad * 8;
        wi[kc] = cvt8(((const float4*)sp)[0], ((const float4*)sp)[1]);
    }

    // ---- per-thread elementwise identity: b = lane, local col k = w ----
    float bias[4];
#pragma unroll
    for (int g = 0; g < 4; ++g) {
        int j2 = g * H_ + p * 8 + w;
        bias[g] = b_ih[j2] + b_hh[j2];
    }
    float c_state = 0.0f;

    const int rot = p >> 3;               // 0..7 chunk-pair rotation

    for (int t = 0; t < T_; ++t) {
        // 1) prefetch + convert this step's x fragments (L2-cached, read-only)
        bf16x8 xf[8];
#pragma unroll
        for (int kc = 0; kc < 8; ++kc) {
            const float* xp = x + ((size_t)arow * T_ + t) * I_ + kc * 32 + quad * 8;
            xf[kc] = cvt8(((const float4*)xp)[0], ((const float4*)xp)[1]);
        }

        f32x4 acc0 = {0.f, 0.f, 0.f, 0.f}, acc1 = {0.f, 0.f, 0.f, 0.f};

        if (t > 0) {
            // 2) h A-fragments: poll-load own packets from L3 until ready,
            //    MFMA each 64-col chunk-pair as it arrives.
            const unsigned long long* hrow = (const unsigned long long*)
                (hs + (size_t)(t - 1) * (B_ * H_) + (size_t)arow * H_);
#pragma unroll
            for (int i = 0; i < 8; ++i) {
                const int kc = ((rot + i) & 7) * 2;
                const unsigned long long* b0 = hrow + kc * 8 + quad * 2;
                const unsigned long long* b1 = hrow + (kc + 1) * 8 + quad * 2;
                unsigned long long va, vb, vc, vd;
                int iters = 0;
                while (true) {
                    va = __hip_atomic_load(b0,     __ATOMIC_RELAXED, __HIP_MEMORY_SCOPE_AGENT);
                    vb = __hip_atomic_load(b0 + 1, __ATOMIC_RELAXED, __HIP_MEMORY_SCOPE_AGENT);
                    vc = __hip_atomic_load(b1,     __ATOMIC_RELAXED, __HIP_MEMORY_SCOPE_AGENT);
                    vd = __hip_atomic_load(b1 + 1, __ATOMIC_RELAXED, __HIP_MEMORY_SCOPE_AGENT);
                    bool ok = (va != SENT) & (vb != SENT) & (vc != SENT) & (vd != SENT);
                    if (__all(ok)) break;
                    __builtin_amdgcn_s_sleep(1);
                    if (++iters > (1 << 18)) break;   // safety valve
                }
                u64x2 ua; ua.x = va; ua.y = vb;
                u64x2 ub; ub.x = vc; ub.y = vd;
                acc0 = __builtin_amdgcn_mfma_f32_16x16x32_bf16(
                           __builtin_bit_cast(bf16x8, ua), wh[kc], acc0, 0, 0, 0);
                acc1 = __builtin_amdgcn_mfma_f32_16x16x32_bf16(
                           __builtin_bit_cast(bf16x8, ub), wh[kc + 1], acc1, 0, 0, 0);
            }
        }

        // 3) x contribution
#pragma unroll
        for (int kc = 0; kc < 8; kc += 2) {
            acc0 = __builtin_amdgcn_mfma_f32_16x16x32_bf16(xf[kc], wi[kc], acc0, 0, 0, 0);
            acc1 = __builtin_amdgcn_mfma_f32_16x16x32_bf16(xf[kc + 1], wi[kc + 1], acc1, 0, 0, 0);
        }
        f32x4 acc = acc0 + acc1;

        // 4) C-frag -> LDS (row = b, col = jl); pad 33 -> conflict-free
#pragma unroll
        for (int r = 0; r < 4; ++r)
            gates_lds[(mt * 16 + quad * 4 + r) * 33 + nt * 16 + l15] = acc[r];
        __syncthreads();   // B1: gates visible

        // 5) elementwise LSTM cell (b = lane, local col k = w); h -> LDS tile
        {
            float gi = gates_lds[lane * 33 + 0 * 8 + w] + bias[0];
            float gf = gates_lds[lane * 33 + 1 * 8 + w] + bias[1];
            float gg = gates_lds[lane * 33 + 2 * 8 + w] + bias[2];
            float go = gates_lds[lane * 33 + 3 * 8 + w] + bias[3];
            float i_s = sigm(gi);
            float f_s = sigm(gf);
            float g_t = tanh_(gg);
            float o_s = sigm(go);
            c_state = f_s * c_state + i_s * g_t;
            float h_new = o_s * tanh_(c_state);
            h_tile[lane * 8 + w] = __builtin_bit_cast(unsigned short, (__bf16)h_new);
        }
        __syncthreads();   // B2: h_tile complete, gates reads done

        // 6) wave 0: gather 16B/row from LDS, push packets to L3, move on.
        //    No drain, no flag — the data itself signals readiness.
        if (w == 0) {
            u64x2 v = *(const u64x2*)&h_tile[lane * 8];
            unsigned long long* dst = (unsigned long long*)
                (hs + (size_t)t * (B_ * H_) + (size_t)lane * H_ + p * 8);
            __hip_atomic_store(dst,     v.x, __ATOMIC_RELAXED, __HIP_MEMORY_SCOPE_AGENT);
            __hip_atomic_store(dst + 1, v.y, __ATOMIC_RELAXED, __HIP_MEMORY_SCOPE_AGENT);
        }
    }
}

// ---------------------------------------------------------------------------
// Output projection: out[b,t,c] = hs[t,b,:] @ W_fc[c,:] + b_fc[c]
// 512 wgs (one per t) x 512 threads; W_fc frags stationary in VGPRs.
// ---------------------------------------------------------------------------
__global__ void __launch_bounds__(512, 2)
out_kernel(const unsigned short* __restrict__ hs, const float* __restrict__ W_fc,
           const float* __restrict__ b_fc, float* __restrict__ out)
{
    const int t    = blockIdx.x;
    const int tid  = threadIdx.x;
    const int w    = tid >> 6;      // c-tile 0..7
    const int lane = tid & 63;
    const int l15  = lane & 15;
    const int quad = lane >> 4;

    bf16x8 wf[16];
#pragma unroll
    for (int kc = 0; kc < 16; ++kc) {
        const float* sp = W_fc + (size_t)(w * 16 + l15) * H_ + kc * 32 + quad * 8;
        wf[kc] = cvt8(((const float4*)sp)[0], ((const float4*)sp)[1]);
    }

    f32x4 acc[4];
#pragma unroll
    for (int m = 0; m < 4; ++m) acc[m] = (f32x4){0.f, 0.f, 0.f, 0.f};

    const unsigned short* hsrow = hs + (size_t)t * (B_ * H_);
#pragma unroll
    for (int kc = 0; kc < 16; ++kc) {
#pragma unroll
        for (int m = 0; m < 4; ++m) {
            bf16x8 a = *(const bf16x8*)(hsrow + (size_t)(m * 16 + l15) * H_ +
                                        kc * 32 + quad * 8);
            acc[m] = __builtin_amdgcn_mfma_f32_16x16x32_bf16(a, wf[kc], acc[m], 0, 0, 0);
        }
    }

    const int c = w * 16 + l15;
    const float bias = b_fc[c];
#pragma unroll
    for (int m = 0; m < 4; ++m) {
#pragma unroll
        for (int r = 0; r < 4; ++r) {
            int b = m * 16 + quad * 4 + r;
            out[(size_t)b * (T_ * C_) + (size_t)t * C_ + c] = acc[m][r] + bias;
        }
    }
}

extern "C" void kernel_launch(void* const* d_in, const int* in_sizes, int n_in,
                              void* d_out, int out_size, void* d_ws, size_t ws_size,
                              hipStream_t stream)
{
    const float* x    = (const float*)d_in[0];
    const float* W_ih = (const float*)d_in[1];
    const float* W_hh = (const float*)d_in[2];
    const float* b_ih = (const float*)d_in[3];
    const float* b_hh = (const float*)d_in[4];
    const float* W_fc = (const float*)d_in[5];
    const float* b_fc = (const float*)d_in[6];
    float* out = (float*)d_out;

    unsigned short* hs = (unsigned short*)d_ws;

    // hs must start as sentinel (bf16 NaN pattern) for data-as-flag polling;
    // d_ws is re-poisoned 0xAA before every replay, so memset every call.
    hipMemsetAsync(hs, 0xFF, HS_BYTES, stream);

    lstm_kernel<<<NWG, 512, 0, stream>>>(x, W_ih, W_hh, b_ih, b_hh, hs);
    out_kernel<<<T_, 512, 0, stream>>>(hs, W_fc, b_fc, out);
}

// Round 5
// 7131.943 us; speedup vs baseline: 1.1153x; 1.1153x over previous
//
#include <hip/hip_runtime.h>

// Problem: B=64, T=512, I=256, H=512, C=128. LSTM forward (truncation is a
// forward no-op) + final linear projection. fp32 in/out; bf16 MFMA inside.
#define B_ 64
#define T_ 512
#define I_ 256
#define H_ 512
#define C_ 128
#define NWG 64                // one wg per 8 h-columns; 32 gate rows each
#define HS_ELEMS ((size_t)T_ * B_ * H_)          // bf16 h archive/broadcast
#define HS_BYTES (HS_ELEMS * 2)                  // 32 MB

typedef __bf16 bf16x8 __attribute__((ext_vector_type(8)));
typedef float f32x4 __attribute__((ext_vector_type(4)));
typedef unsigned long long u64x2 __attribute__((ext_vector_type(2)));

__device__ __forceinline__ bf16x8 cvt8(const float4 a, const float4 b) {
    bf16x8 r;
    r[0] = (__bf16)a.x; r[1] = (__bf16)a.y; r[2] = (__bf16)a.z; r[3] = (__bf16)a.w;
    r[4] = (__bf16)b.x; r[5] = (__bf16)b.y; r[6] = (__bf16)b.z; r[7] = (__bf16)b.w;
    return r;
}

__device__ __forceinline__ float sigm(float x) {
    return __frcp_rn(1.0f + __expf(-x));
}
__device__ __forceinline__ float tanh_(float x) {
    return 2.0f * sigm(2.0f * x) - 1.0f;
}

// ---------------------------------------------------------------------------
// Recurrent kernel: 64 wgs x 512 threads (8 waves). wg p owns h columns
// [8p, 8p+8). Weights stationary in VGPRs.
//
// Sync design v4 — WAVE-AUTONOMOUS, no __syncthreads in the T-loop:
//   Gate-column remap J = (n&3)*H + p*8 + nt*4 + (n>>2): each wave holds all
//   4 gates of its own 4 h-columns, so the gates LDS transpose and the
//   elementwise cell are wave-local (ordered by raw lgkmcnt waits, not
//   barriers). Each wave stores its 16 u64 h-packets (sc1, straight to L3)
//   as soon as IT finishes — no intra-wg convoy. Intra-wg completion is one
//   LDS ds_add per wave (lane 0, after vmcnt(0) store-ACK); the 8th wave
//   resets the counter and stores the per-wg flag. Consumers hard-spin
//   (no s_sleep) on ONE coalesced 256 B flag load + __all ballot, then
//   bulk-load h fully pipelined (poll cheap / load bulk — R4's lesson).
// ---------------------------------------------------------------------------
__global__ void __launch_bounds__(512, 2)
lstm_kernel(const float* __restrict__ x, const float* __restrict__ W_ih,
            const float* __restrict__ W_hh, const float* __restrict__ b_ih,
            const float* __restrict__ b_hh, unsigned short* __restrict__ hs,
            unsigned int* __restrict__ flags)
{
    const int p    = blockIdx.x;          // 0..63
    const int tid  = threadIdx.x;
    const int w    = tid >> 6;            // wave 0..7
    const int lane = tid & 63;
    const int l15  = lane & 15;
    const int quad = lane >> 4;
    const int mt   = w >> 1;              // b-tile 0..3
    const int nt   = w & 1;               // gate-col tile 0..1
    const int arow = mt * 16 + l15;       // A-operand row (batch index b)

    __shared__ float gates_lds[64 * 33];            // [b][col-in-32], pad 33
    __shared__ unsigned long long h_patch[8][16];   // per-wave [l15] u64 pkt
    __shared__ unsigned int scnt;                   // intra-wg completion

    if (tid == 0) scnt = 0;
    __syncthreads();                      // once, before the T-loop

    // ---- stationary weight fragments (B operand: B[k][n], n = lane&15) ----
    // col n -> gate row J: gate = n&3, local h-col = nt*4 + (n>>2)
    const int J = (l15 & 3) * H_ + p * 8 + nt * 4 + (l15 >> 2);
    bf16x8 wh[16], wi[8];
#pragma unroll
    for (int kc = 0; kc < 16; ++kc) {
        const float* sp = W_hh + (size_t)J * H_ + kc * 32 + quad * 8;
        wh[kc] = cvt8(((const float4*)sp)[0], ((const float4*)sp)[1]);
    }
#pragma unroll
    for (int kc = 0; kc < 8; ++kc) {
        const float* sp = W_ih + (size_t)J * I_ + kc * 32 + quad * 8;
        wi[kc] = cvt8(((const float4*)sp)[0], ((const float4*)sp)[1]);
    }

    // ---- elementwise identity: b = mt*16 + l15, h-col hc8 = nt*4 + quad ----
    const int hc8 = nt * 4 + quad;
    float bias[4];
#pragma unroll
    for (int g = 0; g < 4; ++g)
        bias[g] = b_ih[g * H_ + p * 8 + hc8] + b_hh[g * H_ + p * 8 + hc8];
    float c_state = 0.0f;

    for (int t = 0; t < T_; ++t) {
        // 1) prefetch + convert this step's x fragments (L2-cached, read-only)
        bf16x8 xf[8];
#pragma unroll
        for (int kc = 0; kc < 8; ++kc) {
            const float* xp = x + ((size_t)arow * T_ + t) * I_ + kc * 32 + quad * 8;
            xf[kc] = cvt8(((const float4*)xp)[0], ((const float4*)xp)[1]);
        }

        f32x4 acc0 = {0.f, 0.f, 0.f, 0.f}, acc1 = {0.f, 0.f, 0.f, 0.f};

        if (t > 0) {
            // 2) wait: ONE coalesced load of 64 per-wg flags + ballot, hard spin
            const unsigned int* fl = flags + (size_t)(t - 1) * NWG;
            int iters = 0;
            while (true) {
                unsigned int f = __hip_atomic_load(&fl[lane], __ATOMIC_RELAXED,
                                                   __HIP_MEMORY_SCOPE_AGENT);
                if (__all(f != 0)) break;
                if (++iters > (1 << 22)) break;   // safety valve
            }

            // 3) h A-fragments: bulk, fully pipelined sc1 loads from L3
            const unsigned long long* hrow = (const unsigned long long*)
                (hs + (size_t)(t - 1) * (B_ * H_) + (size_t)arow * H_);
#pragma unroll
            for (int kc = 0; kc < 16; kc += 2) {
                u64x2 ua, ub;
                ua.x = __hip_atomic_load(hrow + kc * 8 + quad * 2,
                                         __ATOMIC_RELAXED, __HIP_MEMORY_SCOPE_AGENT);
                ua.y = __hip_atomic_load(hrow + kc * 8 + quad * 2 + 1,
                                         __ATOMIC_RELAXED, __HIP_MEMORY_SCOPE_AGENT);
                ub.x = __hip_atomic_load(hrow + (kc + 1) * 8 + quad * 2,
                                         __ATOMIC_RELAXED, __HIP_MEMORY_SCOPE_AGENT);
                ub.y = __hip_atomic_load(hrow + (kc + 1) * 8 + quad * 2 + 1,
                                         __ATOMIC_RELAXED, __HIP_MEMORY_SCOPE_AGENT);
                acc0 = __builtin_amdgcn_mfma_f32_16x16x32_bf16(
                           __builtin_bit_cast(bf16x8, ua), wh[kc], acc0, 0, 0, 0);
                acc1 = __builtin_amdgcn_mfma_f32_16x16x32_bf16(
                           __builtin_bit_cast(bf16x8, ub), wh[kc + 1], acc1, 0, 0, 0);
            }
        }

        // 4) x contribution
#pragma unroll
        for (int kc = 0; kc < 8; kc += 2) {
            acc0 = __builtin_amdgcn_mfma_f32_16x16x32_bf16(xf[kc], wi[kc], acc0, 0, 0, 0);
            acc1 = __builtin_amdgcn_mfma_f32_16x16x32_bf16(xf[kc + 1], wi[kc + 1], acc1, 0, 0, 0);
        }
        f32x4 acc = acc0 + acc1;

        // 5) C-frag -> wave-private LDS block (rows mt*16.., cols nt*16..).
        //    No barrier: wave-local, ordered by lgkmcnt.
#pragma unroll
        for (int r = 0; r < 4; ++r)
            gates_lds[(mt * 16 + quad * 4 + r) * 33 + nt * 16 + l15] = acc[r];
        asm volatile("s_waitcnt lgkmcnt(0)" ::: "memory");

        // 6) elementwise cell: lane owns (b = mt*16+l15, hc8); its 4 gates
        //    are contiguous at cols nt*16 + quad*4 + g (wave-local read).
        {
            const float* gp = &gates_lds[(size_t)(mt * 16 + l15) * 33 + nt * 16 + quad * 4];
            float i_s = sigm(gp[0] + bias[0]);
            float f_s = sigm(gp[1] + bias[1]);
            float g_t = tanh_(gp[2] + bias[2]);
            float o_s = sigm(gp[3] + bias[3]);
            c_state = f_s * c_state + i_s * g_t;
            float h_new = o_s * tanh_(c_state);
            // gather 4 quads' bf16 into one u64 packet via wave-local LDS
            unsigned short* hp = (unsigned short*)&h_patch[w][l15];
            hp[quad] = __builtin_bit_cast(unsigned short, (__bf16)h_new);
        }
        asm volatile("s_waitcnt lgkmcnt(0)" ::: "memory");

        // 7) this wave alone stores its 16 packets (lanes 0..15), ACKs, and
        //    bumps the wg counter; the 8th wave raises the per-wg flag.
        if (lane < 16) {
            unsigned long long pkt = h_patch[w][lane];
            unsigned long long* dst = (unsigned long long*)
                (hs + (size_t)t * (B_ * H_) + (size_t)(mt * 16 + lane) * H_
                    + p * 8 + nt * 4);
            __hip_atomic_store(dst, pkt, __ATOMIC_RELAXED, __HIP_MEMORY_SCOPE_AGENT);
        }
        asm volatile("s_waitcnt vmcnt(0)" ::: "memory");
        if (lane == 0) {
            unsigned int old = atomicAdd(&scnt, 1u);      // ds_add_rtn
            if (old == 7u) {
                __hip_atomic_store(&scnt, 0u, __ATOMIC_RELAXED,
                                   __HIP_MEMORY_SCOPE_WORKGROUP);
                __hip_atomic_store(&flags[(size_t)t * NWG + p], 1u,
                                   __ATOMIC_RELAXED, __HIP_MEMORY_SCOPE_AGENT);
            }
        }
    }
}

// ---------------------------------------------------------------------------
// Output projection: out[b,t,c] = hs[t,b,:] @ W_fc[c,:] + b_fc[c]
// 512 wgs (one per t) x 512 threads; W_fc frags stationary in VGPRs.
// ---------------------------------------------------------------------------
__global__ void __launch_bounds__(512, 2)
out_kernel(const unsigned short* __restrict__ hs, const float* __restrict__ W_fc,
           const float* __restrict__ b_fc, float* __restrict__ out)
{
    const int t    = blockIdx.x;
    const int tid  = threadIdx.x;
    const int w    = tid >> 6;      // c-tile 0..7
    const int lane = tid & 63;
    const int l15  = lane & 15;
    const int quad = lane >> 4;

    bf16x8 wf[16];
#pragma unroll
    for (int kc = 0; kc < 16; ++kc) {
        const float* sp = W_fc + (size_t)(w * 16 + l15) * H_ + kc * 32 + quad * 8;
        wf[kc] = cvt8(((const float4*)sp)[0], ((const float4*)sp)[1]);
    }

    f32x4 acc[4];
#pragma unroll
    for (int m = 0; m < 4; ++m) acc[m] = (f32x4){0.f, 0.f, 0.f, 0.f};

    const unsigned short* hsrow = hs + (size_t)t * (B_ * H_);
#pragma unroll
    for (int kc = 0; kc < 16; ++kc) {
#pragma unroll
        for (int m = 0; m < 4; ++m) {
            bf16x8 a = *(const bf16x8*)(hsrow + (size_t)(m * 16 + l15) * H_ +
                                        kc * 32 + quad * 8);
            acc[m] = __builtin_amdgcn_mfma_f32_16x16x32_bf16(a, wf[kc], acc[m], 0, 0, 0);
        }
    }

    const int c = w * 16 + l15;
    const float bias = b_fc[c];
#pragma unroll
    for (int m = 0; m < 4; ++m) {
#pragma unroll
        for (int r = 0; r < 4; ++r) {
            int b = m * 16 + quad * 4 + r;
            out[(size_t)b * (T_ * C_) + (size_t)t * C_ + c] = acc[m][r] + bias;
        }
    }
}

extern "C" void kernel_launch(void* const* d_in, const int* in_sizes, int n_in,
                              void* d_out, int out_size, void* d_ws, size_t ws_size,
                              hipStream_t stream)
{
    const float* x    = (const float*)d_in[0];
    const float* W_ih = (const float*)d_in[1];
    const float* W_hh = (const float*)d_in[2];
    const float* b_ih = (const float*)d_in[3];
    const float* b_hh = (const float*)d_in[4];
    const float* W_fc = (const float*)d_in[5];
    const float* b_fc = (const float*)d_in[6];
    float* out = (float*)d_out;

    unsigned short* hs = (unsigned short*)d_ws;
    unsigned int* flags = (unsigned int*)((char*)d_ws + HS_BYTES);

    // flags region is poisoned 0xAA before every replay -> must zero on-stream
    hipMemsetAsync(flags, 0, (size_t)T_ * NWG * sizeof(unsigned int), stream);

    lstm_kernel<<<NWG, 512, 0, stream>>>(x, W_ih, W_hh, b_ih, b_hh, hs, flags);
    out_kernel<<<T_, 512, 0, stream>>>(hs, W_fc, b_fc, out);
}

// Round 6
// 4709.777 us; speedup vs baseline: 1.6889x; 1.5143x over previous
//
#include <hip/hip_runtime.h>

// Problem: B=64, T=512, I=256, H=512, C=128. LSTM forward (truncation is a
// forward no-op) + final linear projection. fp32 in/out; bf16 MFMA inside.
#define B_ 64
#define T_ 512
#define I_ 256
#define H_ 512
#define C_ 128
#define NW 32                  // worker wgs (target: all on one XCD)
#define NLAUNCH 256
#define HS_BYTES ((size_t)T_ * B_ * H_ * 2)      // 32 MB bf16 h archive
#define FLAGS_BYTES ((size_t)T_ * NW * 4)        // 64 KB

typedef __bf16 bf16x8 __attribute__((ext_vector_type(8)));
typedef float f32x4 __attribute__((ext_vector_type(4)));
typedef int i32x4 __attribute__((ext_vector_type(4)));
typedef unsigned long long u64x2 __attribute__((ext_vector_type(2)));

#define MFMA16 __builtin_amdgcn_mfma_f32_16x16x32_bf16

__device__ __forceinline__ bf16x8 cvt8(const float4 a, const float4 b) {
    bf16x8 r;
    r[0] = (__bf16)a.x; r[1] = (__bf16)a.y; r[2] = (__bf16)a.z; r[3] = (__bf16)a.w;
    r[4] = (__bf16)b.x; r[5] = (__bf16)b.y; r[6] = (__bf16)b.z; r[7] = (__bf16)b.w;
    return r;
}
__device__ __forceinline__ float sigm(float x) { return __frcp_rn(1.0f + __expf(-x)); }
__device__ __forceinline__ float tanh_(float x) { return 2.0f * sigm(2.0f * x) - 1.0f; }

// ---------------------------------------------------------------------------
// Recurrent kernel, v5 — SINGLE-XCD TOPOLOGY.
// 256 wgs launched; each reads HW_REG_XCC_ID. Non-XCD0 wgs delay ~50 µs, so
// XCD0's 32 resident wgs claim the 32 worker slots first (1 wg/CU at our VGPR
// count). A census over slot_xcc picks:
//   fast mode (all workers one XCD): h = plain stores/loads via local L2;
//     flags = plain store + sc0 poll loads (L1-bypass, L2-served).
//   slow mode (mixed placement): R3's proven sc1/L3 protocol.
// h loads are plain cached loads in BOTH modes: every hs address is first
// touched only after its producer's flag (no stale L1/L2 line can exist —
// caches are invalidated at kernel dispatch, proven by out_kernel R1-R5).
// wg p owns h cols [16p,16p+16): gate row J(n) = (n&3)*H + p*16 + (n>>2).
// Wave w: m-tile = w>>1 (16 batches), n-pair = w&1 (2x16 gate cols).
// W_hh/W_ih fragments register-stationary (192 VGPRs).
// ---------------------------------------------------------------------------
__global__ void __launch_bounds__(512, 1)
lstm_kernel(const float* __restrict__ x, const float* __restrict__ W_ih,
            const float* __restrict__ W_hh, const float* __restrict__ b_ih,
            const float* __restrict__ b_hh, unsigned short* __restrict__ hs,
            unsigned int* __restrict__ flags, unsigned int* __restrict__ claim,
            unsigned int* __restrict__ slot_xcc)
{
    const int tid  = threadIdx.x;
    const int w    = tid >> 6;
    const int lane = tid & 63;
    const int l15  = lane & 15;
    const int quad = lane >> 4;

    __shared__ int s_slot;
    __shared__ int s_fast;

    unsigned int xcc;
    asm volatile("s_getreg_b32 %0, hwreg(HW_REG_XCC_ID)" : "=s"(xcc));
    xcc &= 0xf;

    if (tid == 0) {
        if (xcc != 0)
            for (int i = 0; i < 32; ++i) __builtin_amdgcn_s_sleep(64);
        s_slot = (int)atomicAdd(claim, 1u);
    }
    __syncthreads();
    const int p = s_slot;
    if (p >= NW) return;                       // non-workers exit

    if (tid == 0)
        __hip_atomic_store(&slot_xcc[p], xcc + 1u, __ATOMIC_RELAXED,
                           __HIP_MEMORY_SCOPE_AGENT);
    {   // census: wait for all 32 claims, check same-XCD
        unsigned int v = 0; int iters = 0;
        while (true) {
            v = __hip_atomic_load(&slot_xcc[lane & (NW - 1)], __ATOMIC_RELAXED,
                                  __HIP_MEMORY_SCOPE_AGENT);
            if (__all(v != 0)) break;
            if (++iters > (1 << 22)) break;
        }
        unsigned int first = __shfl(v, 0);
        int f = __all(v == first) ? 1 : 0;
        if (tid == 0) s_fast = f;
    }
    __syncthreads();
    const bool fast = (s_fast != 0);

    const int mt = w >> 1, npair = w & 1;
    const int arow = mt * 16 + l15;            // A-operand row (batch b)

    __shared__ float gates_lds[64 * 68];       // [b][64 n-cols], pad 68
    __shared__ unsigned short h_tile[64 * 24]; // [b][16 hcols], pad 24 (48 B)

    // stationary weight fragments: B[k][n], n = npair*32 + s*16 + l15
    bf16x8 wh[2][16], wi[2][8];
#pragma unroll
    for (int s = 0; s < 2; ++s) {
        const int n = npair * 32 + s * 16 + l15;
        const int J = (n & 3) * H_ + p * 16 + (n >> 2);
#pragma unroll
        for (int kc = 0; kc < 16; ++kc) {
            const float* sp = W_hh + (size_t)J * H_ + kc * 32 + quad * 8;
            wh[s][kc] = cvt8(((const float4*)sp)[0], ((const float4*)sp)[1]);
        }
#pragma unroll
        for (int kc = 0; kc < 8; ++kc) {
            const float* sp = W_ih + (size_t)J * I_ + kc * 32 + quad * 8;
            wi[s][kc] = cvt8(((const float4*)sp)[0], ((const float4*)sp)[1]);
        }
    }

    // elementwise identity: b = lane (tid&63), hcols w and w+8
    float bias[2][4];
#pragma unroll
    for (int half = 0; half < 2; ++half) {
        const int hc = w + half * 8;
#pragma unroll
        for (int g = 0; g < 4; ++g) {
            const int J = g * H_ + p * 16 + hc;
            bias[half][g] = b_ih[J] + b_hh[J];
        }
    }
    float cst[2] = {0.f, 0.f};

    for (int t = 0; t < T_; ++t) {
        f32x4 acc[2] = {{0.f,0.f,0.f,0.f},{0.f,0.f,0.f,0.f}};

        // 1) x contribution first — independent of the barrier
#pragma unroll
        for (int kc = 0; kc < 8; ++kc) {
            const float* xp = x + ((size_t)arow * T_ + t) * I_ + kc * 32 + quad * 8;
            bf16x8 xa = cvt8(((const float4*)xp)[0], ((const float4*)xp)[1]);
            acc[0] = MFMA16(xa, wi[0][kc], acc[0], 0, 0, 0);
            acc[1] = MFMA16(xa, wi[1][kc], acc[1], 0, 0, 0);
        }

        if (t > 0) {
            // 2) poll 32 per-wg flags: one coalesced load + ballot
            const unsigned int* fl = flags + (size_t)(t - 1) * NW;
            int iters = 0;
            if (fast) {
                while (true) {
                    unsigned int v;
                    asm volatile("global_load_dword %0, %1, off sc0\n\t"
                                 "s_waitcnt vmcnt(0)"
                                 : "=v"(v) : "v"(fl + (lane & 31)) : "memory");
                    if (__all(v != 0)) break;
                    if (++iters > (1 << 24)) break;   // safety valve
                }
            } else {
                while (true) {
                    unsigned int v = __hip_atomic_load(fl + (lane & 31),
                            __ATOMIC_RELAXED, __HIP_MEMORY_SCOPE_AGENT);
                    if (__all(v != 0)) break;
                    if (++iters > (1 << 24)) break;
                }
            }
            asm volatile("" ::: "memory");   // no h-load hoisting above poll

            // 3) h A-fragments: plain cached loads (first-touch-after-ready),
            //    compiler pipelines loads/MFMA with fine-grained waitcnt
            const unsigned short* hrow =
                hs + (size_t)(t - 1) * (B_ * H_) + (size_t)arow * H_;
#pragma unroll
            for (int kc = 0; kc < 16; ++kc) {
                bf16x8 a = *(const bf16x8*)(hrow + kc * 32 + quad * 8);
                acc[0] = MFMA16(a, wh[0][kc], acc[0], 0, 0, 0);
                acc[1] = MFMA16(a, wh[1][kc], acc[1], 0, 0, 0);
            }
        }

        // 4) C-frags -> LDS [b][n]
#pragma unroll
        for (int s = 0; s < 2; ++s)
#pragma unroll
            for (int r = 0; r < 4; ++r)
                gates_lds[(mt * 16 + quad * 4 + r) * 68 + npair * 32 + s * 16 + l15]
                    = acc[s][r];
        __syncthreads();

        // 5) cell: thread owns (b=lane, hc=w) and (b=lane, hc=w+8);
        //    4 gates contiguous at n = 4*hc (float4)
#pragma unroll
        for (int half = 0; half < 2; ++half) {
            const int hc = w + half * 8;
            const float4 g4 = *(const float4*)&gates_lds[lane * 68 + hc * 4];
            float i_s = sigm(g4.x + bias[half][0]);
            float f_s = sigm(g4.y + bias[half][1]);
            float g_t = tanh_(g4.z + bias[half][2]);
            float o_s = sigm(g4.w + bias[half][3]);
            cst[half] = f_s * cst[half] + i_s * g_t;
            float h_new = o_s * tanh_(cst[half]);
            h_tile[lane * 24 + hc] = __builtin_bit_cast(unsigned short, (__bf16)h_new);
        }
        __syncthreads();

        // 6) wave 0: gather 32 B/row, store, ACK, raise flag
        if (w == 0) {
            i32x4 v0 = *(const i32x4*)&h_tile[lane * 24];
            i32x4 v1 = *(const i32x4*)&h_tile[lane * 24 + 8];
            unsigned short* dst =
                hs + (size_t)t * (B_ * H_) + (size_t)lane * H_ + p * 16;
            if (fast) {                    // plain stores -> local L2
                ((i32x4*)dst)[0] = v0;
                ((i32x4*)dst)[1] = v1;
            } else {                       // write-through to L3 (sc1)
                const u64x2 a = __builtin_bit_cast(u64x2, v0);
                const u64x2 b = __builtin_bit_cast(u64x2, v1);
                unsigned long long* d64 = (unsigned long long*)dst;
                __hip_atomic_store(d64 + 0, a.x, __ATOMIC_RELAXED, __HIP_MEMORY_SCOPE_AGENT);
                __hip_atomic_store(d64 + 1, a.y, __ATOMIC_RELAXED, __HIP_MEMORY_SCOPE_AGENT);
                __hip_atomic_store(d64 + 2, b.x, __ATOMIC_RELAXED, __HIP_MEMORY_SCOPE_AGENT);
                __hip_atomic_store(d64 + 3, b.y, __ATOMIC_RELAXED, __HIP_MEMORY_SCOPE_AGENT);
            }
            asm volatile("s_waitcnt vmcnt(0)" ::: "memory");
            if (lane == 0) {
                unsigned int* fp = flags + (size_t)t * NW + p;
                if (fast) {
                    unsigned int one = 1;
                    asm volatile("global_store_dword %0, %1, off sc0"
                                 :: "v"(fp), "v"(one) : "memory");
                } else {
                    __hip_atomic_store(fp, 1u, __ATOMIC_RELAXED,
                                       __HIP_MEMORY_SCOPE_AGENT);
                }
            }
        }
    }
}

// ---------------------------------------------------------------------------
// Output projection: out[b,t,c] = hs[t,b,:] @ W_fc[c,:] + b_fc[c]
// 512 wgs (one per t) x 512 threads; W_fc frags stationary in VGPRs.
// ---------------------------------------------------------------------------
__global__ void __launch_bounds__(512, 2)
out_kernel(const unsigned short* __restrict__ hs, const float* __restrict__ W_fc,
           const float* __restrict__ b_fc, float* __restrict__ out)
{
    const int t    = blockIdx.x;
    const int tid  = threadIdx.x;
    const int w    = tid >> 6;      // c-tile 0..7
    const int lane = tid & 63;
    const int l15  = lane & 15;
    const int quad = lane >> 4;

    bf16x8 wf[16];
#pragma unroll
    for (int kc = 0; kc < 16; ++kc) {
        const float* sp = W_fc + (size_t)(w * 16 + l15) * H_ + kc * 32 + quad * 8;
        wf[kc] = cvt8(((const float4*)sp)[0], ((const float4*)sp)[1]);
    }

    f32x4 acc[4];
#pragma unroll
    for (int m = 0; m < 4; ++m) acc[m] = (f32x4){0.f, 0.f, 0.f, 0.f};

    const unsigned short* hsrow = hs + (size_t)t * (B_ * H_);
#pragma unroll
    for (int kc = 0; kc < 16; ++kc) {
#pragma unroll
        for (int m = 0; m < 4; ++m) {
            bf16x8 a = *(const bf16x8*)(hsrow + (size_t)(m * 16 + l15) * H_ +
                                        kc * 32 + quad * 8);
            acc[m] = MFMA16(a, wf[kc], acc[m], 0, 0, 0);
        }
    }

    const int c = w * 16 + l15;
    const float bias = b_fc[c];
#pragma unroll
    for (int m = 0; m < 4; ++m) {
#pragma unroll
        for (int r = 0; r < 4; ++r) {
            int b = m * 16 + quad * 4 + r;
            out[(size_t)b * (T_ * C_) + (size_t)t * C_ + c] = acc[m][r] + bias;
        }
    }
}

extern "C" void kernel_launch(void* const* d_in, const int* in_sizes, int n_in,
                              void* d_out, int out_size, void* d_ws, size_t ws_size,
                              hipStream_t stream)
{
    const float* x    = (const float*)d_in[0];
    const float* W_ih = (const float*)d_in[1];
    const float* W_hh = (const float*)d_in[2];
    const float* b_ih = (const float*)d_in[3];
    const float* b_hh = (const float*)d_in[4];
    const float* W_fc = (const float*)d_in[5];
    const float* b_fc = (const float*)d_in[6];
    float* out = (float*)d_out;

    unsigned short* hs  = (unsigned short*)d_ws;
    unsigned int* flags = (unsigned int*)((char*)d_ws + HS_BYTES);
    unsigned int* claim = (unsigned int*)((char*)d_ws + HS_BYTES + FLAGS_BYTES);
    unsigned int* sxcc  = (unsigned int*)((char*)d_ws + HS_BYTES + FLAGS_BYTES + 64);

    // flags/claim/census poisoned 0xAA before every replay -> zero on-stream
    hipMemsetAsync(flags, 0, FLAGS_BYTES + 256, stream);

    lstm_kernel<<<NLAUNCH, 512, 0, stream>>>(x, W_ih, W_hh, b_ih, b_hh, hs,
                                             flags, claim, sxcc);
    out_kernel<<<T_, 512, 0, stream>>>(hs, W_fc, b_fc, out);
}